// Round 9
// baseline (354.545 us; speedup 1.0000x reference)
//
#include <hip/hip_runtime.h>
#include <hip/hip_bf16.h>

#define F_IN 128

typedef short bf16x8 __attribute__((ext_vector_type(8)));
typedef short bf16x4 __attribute__((ext_vector_type(4)));
typedef float f32x4  __attribute__((ext_vector_type(4)));
typedef float f32x2  __attribute__((ext_vector_type(2)));

// ---------------- fused bf16-convert (building_x -> xsub) + edge count ----------------
// cnt must be zeroed (hipMemsetAsync) before this kernel.

__global__ void k_prep(const float* __restrict__ X, const int* __restrict__ l2g,
                       const int* __restrict__ dst, ushort* __restrict__ xsub,
                       int* __restrict__ cnt, int n32, int E) {
  int i = blockIdx.x * blockDim.x + threadIdx.x;
  if (i < E) atomicAdd(&cnt[dst[i]], 1);
  if (i < n32) {
    int row = i >> 5, c4 = (i & 31) * 4;
    int g = l2g[row];
    float4 v = *(const float4*)(X + (size_t)g * 128 + c4);
    ushort o[4];
    __hip_bfloat16 h;
    h = __float2bfloat16(v.x); o[0] = *(ushort*)&h;
    h = __float2bfloat16(v.y); o[1] = *(ushort*)&h;
    h = __float2bfloat16(v.z); o[2] = *(ushort*)&h;
    h = __float2bfloat16(v.w); o[3] = *(ushort*)&h;
    uint2 pk;
    pk.x = (uint)o[0] | ((uint)o[1] << 16);
    pk.y = (uint)o[2] | ((uint)o[3] << 16);
    *(uint2*)(xsub + (size_t)row * 128 + c4) = pk;
  }
}

// ---------------- CSR scans (row size = cnt + 1, self-loop at slot 0) ----------------

__global__ void k_scan1(const int* __restrict__ cnt, int* __restrict__ rp,
                        int* __restrict__ bsum, float* __restrict__ dis,
                        int* __restrict__ fill, int n) {
  int tid = threadIdx.x;
  int i = blockIdx.x * 256 + tid;
  int v = (i < n) ? cnt[i] + 1 : 0;       // + self-loop
  int orig = v;
  int lane = tid & 63;
  #pragma unroll
  for (int d = 1; d < 64; d <<= 1) {
    int t = __shfl_up(v, d);
    if (lane >= d) v += t;
  }
  __shared__ int wsum[4];
  int wid = tid >> 6;
  if (lane == 63) wsum[wid] = v;
  __syncthreads();
  int off = 0;
  for (int w = 0; w < wid; ++w) off += wsum[w];
  int incl = v + off;
  if (i < n) {
    rp[i]   = incl - orig;
    dis[i]  = rsqrtf((float)orig);
    fill[i] = 1;                          // slot 0 reserved for self
  }
  if (tid == 255) bsum[blockIdx.x] = incl;
}

__global__ void k_scan2(int* __restrict__ bsum, int nb) {
  __shared__ int s[1024];
  int tid = threadIdx.x;
  int v = (tid < nb) ? bsum[tid] : 0;
  s[tid] = v;
  __syncthreads();
  for (int d = 1; d < 1024; d <<= 1) {
    int t = (tid >= d) ? s[tid - d] : 0;
    __syncthreads();
    s[tid] += t;
    __syncthreads();
  }
  if (tid < nb) bsum[tid] = s[tid] - v;
}

__global__ void k_scan3(int* __restrict__ rp, const int* __restrict__ bsum, int n, int Etot) {
  int i = blockIdx.x * blockDim.x + threadIdx.x;
  if (i < n) rp[i] += bsum[i >> 8];
  if (i == 0) rp[n] = Etot;
}

// edges at slots >=1; self (i, dis_i^2) at slot 0; also pre-fills the output tensor
__global__ void k_fill_csr(const int* __restrict__ src, const int* __restrict__ dst,
                           const int* __restrict__ rp, int* __restrict__ fill,
                           const float* __restrict__ dis,
                           int2* __restrict__ cw, float* __restrict__ out,
                           int E, int n, int outtot) {
  int e = blockIdx.x * blockDim.x + threadIdx.x;
  if (e < outtot) out[e] = -0.69314718055994531f;   // log(1/2)
  if (e < n) {
    float d = dis[e];
    cw[rp[e]] = make_int2(e, __float_as_int(d * d));
  }
  if (e < E) {
    int s = src[e], d = dst[e];
    int pos = rp[d] + atomicAdd(&fill[d], 1);
    cw[pos] = make_int2(s, __float_as_int(dis[s] * dis[d]));
  }
}

// ---------------- aggregation (standalone, layer-2): 4 groups x 16 lanes x 16B --------
// FUSEW3 folds the 128x2 GEMM into the epilogue (writes h3[2] instead of the row).

template <bool BIASRELU, bool FUSEW3>
__global__ void k_aggb(const ushort* __restrict__ X, const int* __restrict__ rp,
                       const int2* __restrict__ cw, const float* __restrict__ bias,
                       const float* __restrict__ W3,
                       ushort* __restrict__ outp, float* __restrict__ h3, int n) {
  int wavei = (int)((blockIdx.x * (size_t)blockDim.x + threadIdx.x) >> 6);
  int lane = threadIdx.x & 63;
  if (wavei >= n) return;
  int q = lane >> 4, ln = lane & 15;
  int e0 = rp[wavei], deg = rp[wavei + 1] - e0;   // >= 1 (self)

  f32x2 acc[4];
  #pragma unroll
  for (int j = 0; j < 4; ++j) acc[j] = f32x2{0.f, 0.f};

  for (int t0 = 0; t0 < deg; t0 += 4) {
    int t = t0 + q;
    if (t < deg) {
      int2 c = cw[e0 + t];
      float w = __int_as_float(c.y);
      uint4 r = *(const uint4*)((const char*)X + (((uint)c.x << 8) + ((uint)ln << 4)));
      uint u[4] = {r.x, r.y, r.z, r.w};
      f32x2 wv = {w, w};
      #pragma unroll
      for (int tt = 0; tt < 4; ++tt) {
        f32x2 v;
        v.x = __uint_as_float(u[tt] << 16);
        v.y = __uint_as_float(u[tt] & 0xffff0000u);
        acc[tt] += wv * v;
      }
    }
  }

  #pragma unroll
  for (int j = 0; j < 4; ++j) {
    acc[j].x += __shfl_xor(acc[j].x, 16);
    acc[j].y += __shfl_xor(acc[j].y, 16);
    acc[j].x += __shfl_xor(acc[j].x, 32);
    acc[j].y += __shfl_xor(acc[j].y, 32);
  }

  if (lane < 16) {
    if (BIASRELU) {
      float4 b0 = *(const float4*)(bias + ln * 8);
      float4 b1 = *(const float4*)(bias + ln * 8 + 4);
      acc[0].x = fmaxf(acc[0].x + b0.x, 0.f);
      acc[0].y = fmaxf(acc[0].y + b0.y, 0.f);
      acc[1].x = fmaxf(acc[1].x + b0.z, 0.f);
      acc[1].y = fmaxf(acc[1].y + b0.w, 0.f);
      acc[2].x = fmaxf(acc[2].x + b1.x, 0.f);
      acc[2].y = fmaxf(acc[2].y + b1.y, 0.f);
      acc[3].x = fmaxf(acc[3].x + b1.z, 0.f);
      acc[3].y = fmaxf(acc[3].y + b1.w, 0.f);
    }
    if (FUSEW3) {
      const float4* w3p = (const float4*)(W3 + ln * 16);
      float p0 = 0.f, p1 = 0.f;
      #pragma unroll
      for (int j2 = 0; j2 < 4; ++j2) {
        float4 wa = w3p[j2];
        p0 = fmaf(acc[j2].x, wa.x, p0);
        p1 = fmaf(acc[j2].x, wa.y, p1);
        p0 = fmaf(acc[j2].y, wa.z, p0);
        p1 = fmaf(acc[j2].y, wa.w, p1);
      }
      p0 += __shfl_xor(p0, 1); p1 += __shfl_xor(p1, 1);
      p0 += __shfl_xor(p0, 2); p1 += __shfl_xor(p1, 2);
      p0 += __shfl_xor(p0, 4); p1 += __shfl_xor(p1, 4);
      p0 += __shfl_xor(p0, 8); p1 += __shfl_xor(p1, 8);
      if (ln == 0) {
        float2 rr = make_float2(p0, p1);
        *(float2*)(h3 + (size_t)wavei * 2) = rr;
      }
    } else {
      uint pk[4];
      #pragma unroll
      for (int j2 = 0; j2 < 4; ++j2) {
        __hip_bfloat16 hx = __float2bfloat16(acc[j2].x);
        __hip_bfloat16 hy = __float2bfloat16(acc[j2].y);
        pk[j2] = (uint)(*(ushort*)&hx) | ((uint)(*(ushort*)&hy) << 16);
      }
      uint4 sv = make_uint4(pk[0], pk[1], pk[2], pk[3]);
      *(uint4*)((char*)outp + (((size_t)wavei << 8) + ((uint)ln << 4))) = sv;
    }
  }
}

// ---------------- W -> fragment-major bf16 repack ----------------

template <int KT, int NT>
__global__ void k_prep_w(const float* __restrict__ W, ushort* __restrict__ WF) {
  int tid = blockIdx.x * 256 + threadIdx.x;
  if (tid >= KT * NT * 64) return;
  int l  = tid & 63;
  int nt = (tid >> 6) % NT;
  int kt = tid / (64 * NT);
  int colc = nt * 16 + (l & 15);
  int kbase = kt * 32 + (l >> 4) * 4;
  ushort v[8];
  #pragma unroll
  for (int j = 0; j < 8; ++j) {
    int k = kbase + (j & 3) + 16 * (j >> 2);
    __hip_bfloat16 h = __float2bfloat16(W[(size_t)k * (NT * 16) + colc]);
    v[j] = *(ushort*)&h;
  }
  uint4 pk;
  pk.x = (uint)v[0] | ((uint)v[1] << 16);
  pk.y = (uint)v[2] | ((uint)v[3] << 16);
  pk.z = (uint)v[4] | ((uint)v[5] << 16);
  pk.w = (uint)v[6] | ((uint)v[7] << 16);
  *(uint4*)(WF + (size_t)tid * 8) = pk;
}

// ---------------- FUSED layer-1: aggregate -> LDS -> wave-spec MFMA GEMM --------------
// Block = 256 threads (4 waves), 128 nodes. Wave w aggregates nodes [w*32, w*32+32)
// directly into the XOR-swizzled LDS staging tile, then the block runs the
// register-resident-W GEMM (wave w owns N-slice [w*NTW*16, ...)).

template <int KT, int NTW>
__global__ __launch_bounds__(256) void k_agg_gemm(const ushort* __restrict__ X,
                                                  const int* __restrict__ rp,
                                                  const int2* __restrict__ cw,
                                                  const ushort* __restrict__ WF,
                                                  const float* __restrict__ bias,
                                                  ushort* __restrict__ Cout, int n) {
  constexpr int K   = KT * 32;
  constexpr int NT  = NTW * 4;
  constexpr int N   = NT * 16;
  constexpr int CPR = K / 8;                   // 16B chunks per row (=16)
  __shared__ short lds[128 * CPR * 8];

  int tid = threadIdx.x;
  int r0 = blockIdx.x * 128;
  int l  = tid & 63;
  int w  = tid >> 6;
  int hi = l >> 4;

  // preload this wave's W-slice + bias (independent of aggregation)
  bf16x8 wreg[KT * NTW];
  #pragma unroll
  for (int kt = 0; kt < KT; ++kt)
    #pragma unroll
    for (int nt = 0; nt < NTW; ++nt)
      wreg[kt * NTW + nt] =
          *(const bf16x8*)(WF + ((size_t)(kt * NT + w * NTW + nt) * 64 + l) * 8);
  float4 bb[NTW];
  #pragma unroll
  for (int nt = 0; nt < NTW; ++nt)
    bb[nt] = *(const float4*)(bias + (w * NTW + nt) * 16 + hi * 4);

  // ---- aggregation phase: wave w fills LDS rows [w*32, w*32+32) ----
  int q = l >> 4, ln = l & 15;
  for (int k = 0; k < 32; ++k) {
    int rloc = w * 32 + k;
    int node = r0 + rloc;
    if (node < n) {
      int e0 = rp[node], deg = rp[node + 1] - e0;   // >= 1 (self at slot 0)
      f32x2 acc[4];
      #pragma unroll
      for (int j = 0; j < 4; ++j) acc[j] = f32x2{0.f, 0.f};
      for (int t0 = 0; t0 < deg; t0 += 4) {
        int t = t0 + q;
        if (t < deg) {
          int2 c = cw[e0 + t];
          float wv_ = __int_as_float(c.y);
          uint4 r = *(const uint4*)((const char*)X + (((uint)c.x << 8) + ((uint)ln << 4)));
          uint u[4] = {r.x, r.y, r.z, r.w};
          f32x2 wv = {wv_, wv_};
          #pragma unroll
          for (int tt = 0; tt < 4; ++tt) {
            f32x2 v;
            v.x = __uint_as_float(u[tt] << 16);
            v.y = __uint_as_float(u[tt] & 0xffff0000u);
            acc[tt] += wv * v;
          }
        }
      }
      #pragma unroll
      for (int j = 0; j < 4; ++j) {
        acc[j].x += __shfl_xor(acc[j].x, 16);
        acc[j].y += __shfl_xor(acc[j].y, 16);
        acc[j].x += __shfl_xor(acc[j].x, 32);
        acc[j].y += __shfl_xor(acc[j].y, 32);
      }
      if (l < 16) {
        uint pk[4];
        #pragma unroll
        for (int j2 = 0; j2 < 4; ++j2) {
          __hip_bfloat16 hx = __float2bfloat16(acc[j2].x);
          __hip_bfloat16 hy = __float2bfloat16(acc[j2].y);
          pk[j2] = (uint)(*(ushort*)&hx) | ((uint)(*(ushort*)&hy) << 16);
        }
        uint4 sv = make_uint4(pk[0], pk[1], pk[2], pk[3]);
        *(uint4*)(&lds[rloc * CPR * 8 + ((ln ^ (rloc & 15)) * 8)]) = sv;
      }
    }
  }
  __syncthreads();

  // ---- GEMM phase (identical to wave-spec GEMM) ----
  int sw = l & 15;
  #pragma unroll
  for (int s = 0; s < 8; ++s) {
    int rowl = s * 16 + (l & 15);
    bf16x8 xf[KT];
    #pragma unroll
    for (int kt = 0; kt < KT; ++kt) {
      int c0 = kt * 4 + (hi >> 1);
      int within = (hi & 1) * 4;
      bf16x4 lo = *(const bf16x4*)(&lds[rowl * CPR * 8 + (c0 ^ sw) * 8 + within]);
      bf16x4 hx = *(const bf16x4*)(&lds[rowl * CPR * 8 + ((c0 + 2) ^ sw) * 8 + within]);
      bf16x8 a;
      a[0] = lo[0]; a[1] = lo[1]; a[2] = lo[2]; a[3] = lo[3];
      a[4] = hx[0]; a[5] = hx[1]; a[6] = hx[2]; a[7] = hx[3];
      xf[kt] = a;
    }

    f32x4 acc[NTW];
    #pragma unroll
    for (int nt = 0; nt < NTW; ++nt) acc[nt] = f32x4{0.f, 0.f, 0.f, 0.f};
    #pragma unroll
    for (int nt = 0; nt < NTW; ++nt)
      #pragma unroll
      for (int kt = 0; kt < KT; ++kt)
        acc[nt] = __builtin_amdgcn_mfma_f32_16x16x32_bf16(wreg[kt * NTW + nt], xf[kt],
                                                          acc[nt], 0, 0, 0);

    int grow = r0 + s * 16 + (l & 15);
    if (grow < n) {
      #pragma unroll
      for (int nt = 0; nt < NTW; ++nt) {
        int f0 = (w * NTW + nt) * 16 + hi * 4;
        float v0 = fmaxf(acc[nt][0] + bb[nt].x, 0.0f);
        float v1 = fmaxf(acc[nt][1] + bb[nt].y, 0.0f);
        float v2 = fmaxf(acc[nt][2] + bb[nt].z, 0.0f);
        float v3 = fmaxf(acc[nt][3] + bb[nt].w, 0.0f);
        ushort o[4];
        __hip_bfloat16 h;
        h = __float2bfloat16(v0); o[0] = *(ushort*)&h;
        h = __float2bfloat16(v1); o[1] = *(ushort*)&h;
        h = __float2bfloat16(v2); o[2] = *(ushort*)&h;
        h = __float2bfloat16(v3); o[3] = *(ushort*)&h;
        uint2 pk;
        pk.x = (uint)o[0] | ((uint)o[1] << 16);
        pk.y = (uint)o[2] | ((uint)o[3] << 16);
        *(uint2*)(Cout + (size_t)grow * N + f0) = pk;
      }
    }
  }
}

// ---------------- wave-N-specialized MFMA GEMM (layer 2) ----------------

template <int KT, int NTW, bool OUTBF16, bool BIASRELU>
__global__ __launch_bounds__(256) void k_gemm_wspec(const ushort* __restrict__ A,
                                                    const ushort* __restrict__ WF,
                                                    const float* __restrict__ bias,
                                                    void* __restrict__ Cout, int n) {
  constexpr int K   = KT * 32;
  constexpr int NT  = NTW * 4;
  constexpr int N   = NT * 16;
  constexpr int CPR = K / 8;
  __shared__ short lds[128 * CPR * 8];

  int tid = threadIdx.x;
  int r0 = blockIdx.x * 128;
  int l  = tid & 63;
  int w  = tid >> 6;
  int hi = l >> 4;

  bf16x8 wreg[KT * NTW];
  #pragma unroll
  for (int kt = 0; kt < KT; ++kt)
    #pragma unroll
    for (int nt = 0; nt < NTW; ++nt)
      wreg[kt * NTW + nt] =
          *(const bf16x8*)(WF + ((size_t)(kt * NT + w * NTW + nt) * 64 + l) * 8);

  float4 bb[NTW];
  if (BIASRELU) {
    #pragma unroll
    for (int nt = 0; nt < NTW; ++nt)
      bb[nt] = *(const float4*)(bias + (w * NTW + nt) * 16 + hi * 4);
  }

  #pragma unroll
  for (int p = 0; p < (128 * CPR) / 256; ++p) {
    int idx = p * 256 + tid;
    int row = idx / CPR, c = idx % CPR;
    uint4 v = make_uint4(0u, 0u, 0u, 0u);
    if (r0 + row < n) v = *(const uint4*)(A + (size_t)(r0 + row) * K + c * 8);
    *(uint4*)(&lds[row * CPR * 8 + ((c ^ (row & 15))) * 8]) = v;
  }
  __syncthreads();

  int sw = l & 15;
  #pragma unroll
  for (int s = 0; s < 8; ++s) {
    int rowl = s * 16 + (l & 15);
    bf16x8 xf[KT];
    #pragma unroll
    for (int kt = 0; kt < KT; ++kt) {
      int c0 = kt * 4 + (hi >> 1);
      int within = (hi & 1) * 4;
      bf16x4 lo = *(const bf16x4*)(&lds[rowl * CPR * 8 + (c0 ^ sw) * 8 + within]);
      bf16x4 hx = *(const bf16x4*)(&lds[rowl * CPR * 8 + ((c0 + 2) ^ sw) * 8 + within]);
      bf16x8 a;
      a[0] = lo[0]; a[1] = lo[1]; a[2] = lo[2]; a[3] = lo[3];
      a[4] = hx[0]; a[5] = hx[1]; a[6] = hx[2]; a[7] = hx[3];
      xf[kt] = a;
    }

    f32x4 acc[NTW];
    #pragma unroll
    for (int nt = 0; nt < NTW; ++nt) acc[nt] = f32x4{0.f, 0.f, 0.f, 0.f};
    #pragma unroll
    for (int nt = 0; nt < NTW; ++nt)
      #pragma unroll
      for (int kt = 0; kt < KT; ++kt)
        acc[nt] = __builtin_amdgcn_mfma_f32_16x16x32_bf16(wreg[kt * NTW + nt], xf[kt],
                                                          acc[nt], 0, 0, 0);

    int grow = r0 + s * 16 + (l & 15);
    if (grow < n) {
      #pragma unroll
      for (int nt = 0; nt < NTW; ++nt) {
        int f0 = (w * NTW + nt) * 16 + hi * 4;
        float v0 = acc[nt][0], v1 = acc[nt][1], v2 = acc[nt][2], v3 = acc[nt][3];
        if (BIASRELU) {
          v0 = fmaxf(v0 + bb[nt].x, 0.0f);
          v1 = fmaxf(v1 + bb[nt].y, 0.0f);
          v2 = fmaxf(v2 + bb[nt].z, 0.0f);
          v3 = fmaxf(v3 + bb[nt].w, 0.0f);
        }
        if (OUTBF16) {
          ushort o[4];
          __hip_bfloat16 h;
          h = __float2bfloat16(v0); o[0] = *(ushort*)&h;
          h = __float2bfloat16(v1); o[1] = *(ushort*)&h;
          h = __float2bfloat16(v2); o[2] = *(ushort*)&h;
          h = __float2bfloat16(v3); o[3] = *(ushort*)&h;
          uint2 pk;
          pk.x = (uint)o[0] | ((uint)o[1] << 16);
          pk.y = (uint)o[2] | ((uint)o[3] << 16);
          *(uint2*)((ushort*)Cout + (size_t)grow * N + f0) = pk;
        } else {
          f32x4 pk = {v0, v1, v2, v3};
          *(f32x4*)((float*)Cout + (size_t)grow * N + f0) = pk;
        }
      }
    }
  }
}

// ---------------- final: aggregate h3 + bias + log_softmax scatter ----------------

__global__ void k_agg3(const float* __restrict__ h3, const int* __restrict__ rp,
                       const int2* __restrict__ cw, const float* __restrict__ b3,
                       const int* __restrict__ l2g, float* __restrict__ out, int n) {
  int i = blockIdx.x * blockDim.x + threadIdx.x;
  if (i >= n) return;
  float a0 = 0.f, a1 = 0.f;
  int e0 = rp[i], e1 = rp[i + 1];
  for (int e = e0; e < e1; ++e) {
    int2 c = cw[e];
    float w = __int_as_float(c.y);
    a0 = fmaf(w, h3[(size_t)c.x * 2 + 0], a0);
    a1 = fmaf(w, h3[(size_t)c.x * 2 + 1], a1);
  }
  a0 += b3[0];
  a1 += b3[1];
  float m = fmaxf(a0, a1);
  float lse = m + logf(expf(a0 - m) + expf(a1 - m));
  int g = l2g[i];
  out[(size_t)g * 2 + 0] = a0 - lse;
  out[(size_t)g * 2 + 1] = a1 - lse;
}

// ---------------- launch ----------------

extern "C" void kernel_launch(void* const* d_in, const int* in_sizes, int n_in,
                              void* d_out, int out_size, void* d_ws, size_t ws_size,
                              hipStream_t stream) {
  const float* building_x = (const float*)d_in[0];
  const int*   l2g        = (const int*)d_in[1];
  const int*   esrc       = (const int*)d_in[2];
  const int*   edst       = (const int*)d_in[3];
  const float* W1 = (const float*)d_in[4];
  const float* b1 = (const float*)d_in[5];
  const float* W2 = (const float*)d_in[6];
  const float* b2 = (const float*)d_in[7];
  const float* W3 = (const float*)d_in[8];
  const float* b3 = (const float*)d_in[9];
  float* out = (float*)d_out;

  const int n_total = in_sizes[0] / F_IN;
  const int n_sub   = in_sizes[1];
  const int E       = in_sizes[2];
  const int Etot    = E + n_sub;          // edges + self-loops
  const int nb      = (n_sub + 255) / 256;

  // ---- workspace ----
  char* base = (char*)d_ws;
  auto al = [](size_t x) { return (x + 255) & ~(size_t)255; };
  size_t t128 = al((size_t)n_sub * 128 * 2);
  size_t t256 = al((size_t)n_sub * 256 * 2);
  ushort* xsub = (ushort*)base;                    // layer-1 gather table
  ushort* x1   = (ushort*)(base + t128);           // gemm1 out
  ushort* h2b  = (ushort*)(base + t128 + t256);    // gemm2 out (layer-2 gather table)
  size_t off = t128 + t256 + t128;
  auto alloc = [&](size_t bytes) -> void* {
    void* p = base + off;
    off += al(bytes);
    return p;
  };
  float* h3   = (float*)alloc((size_t)n_sub * 2 * 4);
  int*   cnt  = (int*)alloc((size_t)n_sub * 4);
  int*   fill = (int*)alloc((size_t)n_sub * 4);
  int*   rp   = (int*)alloc((size_t)(n_sub + 1) * 4);
  float* dis  = (float*)alloc((size_t)n_sub * 4);
  int2*  cw   = (int2*)alloc((size_t)Etot * 8);
  int*   bsum = (int*)alloc((size_t)nb * 4);
  ushort* w1f = (ushort*)alloc((size_t)128 * 256 * 2);
  ushort* w2f = (ushort*)alloc((size_t)256 * 128 * 2);
  (void)ws_size; (void)n_in; (void)out_size;

  const int B = 256;

  // zero edge counts (DMA), repack weights, fused convert+count
  hipMemsetAsync(cnt, 0, (size_t)n_sub * 4, stream);
  k_prep_w<4, 16><<<16, 256, 0, stream>>>(W1, w1f);
  k_prep_w<8, 8><<<16, 256, 0, stream>>>(W2, w2f);
  int prepGrid = ((n_sub * 32 > E ? n_sub * 32 : E) + B - 1) / B;
  k_prep<<<prepGrid, B, 0, stream>>>(building_x, l2g, edst, xsub, cnt, n_sub * 32, E);

  // CSR scans + fill (also pre-fills output with log(1/2))
  k_scan1<<<nb, 256, 0, stream>>>(cnt, rp, bsum, dis, fill, n_sub);
  k_scan2<<<1, 1024, 0, stream>>>(bsum, nb);
  k_scan3<<<(n_sub + B - 1) / B, B, 0, stream>>>(rp, bsum, n_sub, Etot);
  int fillGrid = ((E > 2 * n_total ? E : 2 * n_total) + B - 1) / B;
  k_fill_csr<<<fillGrid, B, 0, stream>>>(esrc, edst, rp, fill, dis, cw, out,
                                         E, n_sub, 2 * n_total);

  int aggBlocks  = (n_sub + 3) / 4;       // 4 waves / 256-thread block
  int gemmBlocks = (n_sub + 127) / 128;   // BM=128

  // Layer 1 (FUSED): aggregate -> LDS -> MFMA GEMM + bias + relu -> bf16 x1
  k_agg_gemm<4, 4><<<gemmBlocks, 256, 0, stream>>>(xsub, rp, cw, w1f, b1, x1, n_sub);

  // Layer 2: MFMA GEMM (x1 @ W2) -> bf16 h2b, then fused aggregate+bias+relu+W3 -> h3
  k_gemm_wspec<8, 2, true, false><<<gemmBlocks, 256, 0, stream>>>(x1, w2f, nullptr, h2b, n_sub);
  k_aggb<true, true><<<aggBlocks, B, 0, stream>>>(h2b, rp, cw, b2, W3,
                                                  nullptr, h3, n_sub);

  // Layer 3: aggregate h3 + bias + log_softmax scatter
  k_agg3<<<(n_sub + B - 1) / B, B, 0, stream>>>(h3, rp, cw, b3, l2g, out, n_sub);
}

// Round 10
// 272.959 us; speedup vs baseline: 1.2989x; 1.2989x over previous
//
#include <hip/hip_runtime.h>
#include <hip/hip_bf16.h>

#define F_IN 128

typedef short bf16x8 __attribute__((ext_vector_type(8)));
typedef short bf16x4 __attribute__((ext_vector_type(4)));
typedef float f32x4  __attribute__((ext_vector_type(4)));
typedef float f32x2  __attribute__((ext_vector_type(2)));

// ---------------- fused bf16-convert (building_x -> xsub) + edge count ----------------
// cnt must be zeroed (hipMemsetAsync) before this kernel.

__global__ void k_prep(const float* __restrict__ X, const int* __restrict__ l2g,
                       const int* __restrict__ dst, ushort* __restrict__ xsub,
                       int* __restrict__ cnt, int n32, int E) {
  int i = blockIdx.x * blockDim.x + threadIdx.x;
  if (i < E) atomicAdd(&cnt[dst[i]], 1);
  if (i < n32) {
    int row = i >> 5, c4 = (i & 31) * 4;
    int g = l2g[row];
    float4 v = *(const float4*)(X + (size_t)g * 128 + c4);
    ushort o[4];
    __hip_bfloat16 h;
    h = __float2bfloat16(v.x); o[0] = *(ushort*)&h;
    h = __float2bfloat16(v.y); o[1] = *(ushort*)&h;
    h = __float2bfloat16(v.z); o[2] = *(ushort*)&h;
    h = __float2bfloat16(v.w); o[3] = *(ushort*)&h;
    uint2 pk;
    pk.x = (uint)o[0] | ((uint)o[1] << 16);
    pk.y = (uint)o[2] | ((uint)o[3] << 16);
    *(uint2*)(xsub + (size_t)row * 128 + c4) = pk;
  }
}

// ---------------- CSR scans (row size = cnt + 1, self-loop at slot 0) ----------------

__global__ void k_scan1(const int* __restrict__ cnt, int* __restrict__ rp,
                        int* __restrict__ bsum, float* __restrict__ dis,
                        int* __restrict__ fill, int n) {
  int tid = threadIdx.x;
  int i = blockIdx.x * 256 + tid;
  int v = (i < n) ? cnt[i] + 1 : 0;       // + self-loop
  int orig = v;
  int lane = tid & 63;
  #pragma unroll
  for (int d = 1; d < 64; d <<= 1) {
    int t = __shfl_up(v, d);
    if (lane >= d) v += t;
  }
  __shared__ int wsum[4];
  int wid = tid >> 6;
  if (lane == 63) wsum[wid] = v;
  __syncthreads();
  int off = 0;
  for (int w = 0; w < wid; ++w) off += wsum[w];
  int incl = v + off;
  if (i < n) {
    rp[i]   = incl - orig;
    dis[i]  = rsqrtf((float)orig);
    fill[i] = 1;                          // slot 0 reserved for self
  }
  if (tid == 255) bsum[blockIdx.x] = incl;
}

__global__ void k_scan2(int* __restrict__ bsum, int nb) {
  __shared__ int s[1024];
  int tid = threadIdx.x;
  int v = (tid < nb) ? bsum[tid] : 0;
  s[tid] = v;
  __syncthreads();
  for (int d = 1; d < 1024; d <<= 1) {
    int t = (tid >= d) ? s[tid - d] : 0;
    __syncthreads();
    s[tid] += t;
    __syncthreads();
  }
  if (tid < nb) bsum[tid] = s[tid] - v;
}

__global__ void k_scan3(int* __restrict__ rp, const int* __restrict__ bsum, int n, int Etot) {
  int i = blockIdx.x * blockDim.x + threadIdx.x;
  if (i < n) rp[i] += bsum[i >> 8];
  if (i == 0) rp[n] = Etot;
}

// edges at slots >=1; self (i, dis_i^2) at slot 0; also pre-fills the output tensor
__global__ void k_fill_csr(const int* __restrict__ src, const int* __restrict__ dst,
                           const int* __restrict__ rp, int* __restrict__ fill,
                           const float* __restrict__ dis,
                           int2* __restrict__ cw, float* __restrict__ out,
                           int E, int n, int outtot) {
  int e = blockIdx.x * blockDim.x + threadIdx.x;
  if (e < outtot) out[e] = -0.69314718055994531f;   // log(1/2)
  if (e < n) {
    float d = dis[e];
    cw[rp[e]] = make_int2(e, __float_as_int(d * d));
  }
  if (e < E) {
    int s = src[e], d = dst[e];
    int pos = rp[d] + atomicAdd(&fill[d], 1);
    cw[pos] = make_int2(s, __float_as_int(dis[s] * dis[d]));
  }
}

// ---------------- aggregation (standalone): 4 groups x 16 lanes x 16B, masked tail ----
// FUSEW3 folds the 128x2 GEMM into the epilogue (writes h3[2] instead of the row).

template <bool BIASRELU, bool FUSEW3>
__global__ void k_aggb(const ushort* __restrict__ X, const int* __restrict__ rp,
                       const int2* __restrict__ cw, const float* __restrict__ bias,
                       const float* __restrict__ W3,
                       ushort* __restrict__ outp, float* __restrict__ h3, int n) {
  int wavei = (int)((blockIdx.x * (size_t)blockDim.x + threadIdx.x) >> 6);
  int lane = threadIdx.x & 63;
  if (wavei >= n) return;
  int q = lane >> 4, ln = lane & 15;
  int e0 = rp[wavei], deg = rp[wavei + 1] - e0;   // >= 1 (self)

  f32x2 acc[4];
  #pragma unroll
  for (int j = 0; j < 4; ++j) acc[j] = f32x2{0.f, 0.f};

  for (int t0 = 0; t0 < deg; t0 += 4) {
    int t = t0 + q;
    if (t < deg) {
      int2 c = cw[e0 + t];
      float w = __int_as_float(c.y);
      uint4 r = *(const uint4*)((const char*)X + (((uint)c.x << 8) + ((uint)ln << 4)));
      uint u[4] = {r.x, r.y, r.z, r.w};
      f32x2 wv = {w, w};
      #pragma unroll
      for (int tt = 0; tt < 4; ++tt) {
        f32x2 v;
        v.x = __uint_as_float(u[tt] << 16);
        v.y = __uint_as_float(u[tt] & 0xffff0000u);
        acc[tt] += wv * v;
      }
    }
  }

  #pragma unroll
  for (int j = 0; j < 4; ++j) {
    acc[j].x += __shfl_xor(acc[j].x, 16);
    acc[j].y += __shfl_xor(acc[j].y, 16);
    acc[j].x += __shfl_xor(acc[j].x, 32);
    acc[j].y += __shfl_xor(acc[j].y, 32);
  }

  if (lane < 16) {
    if (BIASRELU) {
      float4 b0 = *(const float4*)(bias + ln * 8);
      float4 b1 = *(const float4*)(bias + ln * 8 + 4);
      acc[0].x = fmaxf(acc[0].x + b0.x, 0.f);
      acc[0].y = fmaxf(acc[0].y + b0.y, 0.f);
      acc[1].x = fmaxf(acc[1].x + b0.z, 0.f);
      acc[1].y = fmaxf(acc[1].y + b0.w, 0.f);
      acc[2].x = fmaxf(acc[2].x + b1.x, 0.f);
      acc[2].y = fmaxf(acc[2].y + b1.y, 0.f);
      acc[3].x = fmaxf(acc[3].x + b1.z, 0.f);
      acc[3].y = fmaxf(acc[3].y + b1.w, 0.f);
    }
    if (FUSEW3) {
      const float4* w3p = (const float4*)(W3 + ln * 16);
      float p0 = 0.f, p1 = 0.f;
      #pragma unroll
      for (int j2 = 0; j2 < 4; ++j2) {
        float4 wa = w3p[j2];
        p0 = fmaf(acc[j2].x, wa.x, p0);
        p1 = fmaf(acc[j2].x, wa.y, p1);
        p0 = fmaf(acc[j2].y, wa.z, p0);
        p1 = fmaf(acc[j2].y, wa.w, p1);
      }
      p0 += __shfl_xor(p0, 1); p1 += __shfl_xor(p1, 1);
      p0 += __shfl_xor(p0, 2); p1 += __shfl_xor(p1, 2);
      p0 += __shfl_xor(p0, 4); p1 += __shfl_xor(p1, 4);
      p0 += __shfl_xor(p0, 8); p1 += __shfl_xor(p1, 8);
      if (ln == 0) {
        float2 rr = make_float2(p0, p1);
        *(float2*)(h3 + (size_t)wavei * 2) = rr;
      }
    } else {
      uint pk[4];
      #pragma unroll
      for (int j2 = 0; j2 < 4; ++j2) {
        __hip_bfloat16 hx = __float2bfloat16(acc[j2].x);
        __hip_bfloat16 hy = __float2bfloat16(acc[j2].y);
        pk[j2] = (uint)(*(ushort*)&hx) | ((uint)(*(ushort*)&hy) << 16);
      }
      uint4 sv = make_uint4(pk[0], pk[1], pk[2], pk[3]);
      *(uint4*)((char*)outp + (((size_t)wavei << 8) + ((uint)ln << 4))) = sv;
    }
  }
}

// ---------------- W -> fragment-major bf16 repack ----------------
// lane l holds W[k = kt*32 + (l>>4)*4 + (j&3) + 16*(j>>2)][col = nt*16 + (l&15)]

template <int KT, int NT>
__global__ void k_prep_w(const float* __restrict__ W, ushort* __restrict__ WF) {
  int tid = blockIdx.x * 256 + threadIdx.x;
  if (tid >= KT * NT * 64) return;
  int l  = tid & 63;
  int nt = (tid >> 6) % NT;
  int kt = tid / (64 * NT);
  int colc = nt * 16 + (l & 15);
  int kbase = kt * 32 + (l >> 4) * 4;
  ushort v[8];
  #pragma unroll
  for (int j = 0; j < 8; ++j) {
    int k = kbase + (j & 3) + 16 * (j >> 2);
    __hip_bfloat16 h = __float2bfloat16(W[(size_t)k * (NT * 16) + colc]);
    v[j] = *(ushort*)&h;
  }
  uint4 pk;
  pk.x = (uint)v[0] | ((uint)v[1] << 16);
  pk.y = (uint)v[2] | ((uint)v[3] << 16);
  pk.z = (uint)v[4] | ((uint)v[5] << 16);
  pk.w = (uint)v[6] | ((uint)v[7] << 16);
  *(uint4*)(WF + (size_t)tid * 8) = pk;
}

// ---------------- FUSED GEMM1+GEMM2: xt[n,128] -> h2 = relu(xt@W1+b1)@W2 -> bf16 ------
// Block = 256 threads (4 waves), BM = 128 rows.
// gemm1: wave w owns output cols [w*64, w*64+64) (W1 frags in registers).
// Handoff: those cols ARE gemm2's k-slice (k-tiles 2w, 2w+1); the gemm1 output
// fragment layout equals the gemm2 A-fragment layout:
//   xf2[kt2][j] = bf16(relu(acc[kt2*2+(j>>2)][j&3] + b1)).
// gemm2: each wave computes a 16x128 partial (its k-slice) per row-subtile;
// partials summed across the 4 waves via XOR-swizzled LDS, stored bf16.

__global__ __launch_bounds__(256) void k_gemm12(const ushort* __restrict__ A,
                                                const ushort* __restrict__ WF1,
                                                const ushort* __restrict__ WF2,
                                                const float* __restrict__ bias1,
                                                ushort* __restrict__ H2, int n) {
  __shared__ short stage[128 * 128];       // 32 KB bf16 input tile
  __shared__ float red[4][16][128];        // 32 KB f32 partial-sum buffer

  int tid = threadIdx.x;
  int r0 = blockIdx.x * 128;
  int l  = tid & 63;
  int w  = tid >> 6;
  int hi = l >> 4;

  // W1 fragments for this wave's N-slice (cols w*64..w*64+63): nt = w*4..w*4+3
  bf16x8 wreg1[16];
  #pragma unroll
  for (int kt = 0; kt < 4; ++kt)
    #pragma unroll
    for (int nt = 0; nt < 4; ++nt)
      wreg1[kt * 4 + nt] =
          *(const bf16x8*)(WF1 + ((size_t)(kt * 16 + w * 4 + nt) * 64 + l) * 8);

  // W2 fragments for this wave's k-slice (k-tiles 2w, 2w+1), all 8 n-tiles
  bf16x8 wreg2[16];
  #pragma unroll
  for (int kt2 = 0; kt2 < 2; ++kt2)
    #pragma unroll
    for (int nt2 = 0; nt2 < 8; ++nt2)
      wreg2[kt2 * 8 + nt2] =
          *(const bf16x8*)(WF2 + ((size_t)((w * 2 + kt2) * 8 + nt2) * 64 + l) * 8);

  // bias1 for this wave's col slice
  float bb[4][4];
  #pragma unroll
  for (int nt = 0; nt < 4; ++nt) {
    float4 b4 = *(const float4*)(bias1 + (w * 4 + nt) * 16 + hi * 4);
    bb[nt][0] = b4.x; bb[nt][1] = b4.y; bb[nt][2] = b4.z; bb[nt][3] = b4.w;
  }

  // stage xt tile (coalesced 16B loads, XOR-swizzled 16B chunks; 16 chunks/row)
  #pragma unroll
  for (int p = 0; p < 8; ++p) {
    int idx = p * 256 + tid;
    int row = idx >> 4, c = idx & 15;
    uint4 v = make_uint4(0u, 0u, 0u, 0u);
    if (r0 + row < n) v = *(const uint4*)(A + (size_t)(r0 + row) * 128 + c * 8);
    *(uint4*)(&stage[row * 128 + ((c ^ (row & 15)) * 8)]) = v;
  }
  __syncthreads();

  int sw = l & 15;
  for (int s = 0; s < 8; ++s) {
    int rowl = s * 16 + (l & 15);
    // gemm1 X-fragments from LDS
    bf16x8 xf[4];
    #pragma unroll
    for (int kt = 0; kt < 4; ++kt) {
      int c0 = kt * 4 + (hi >> 1);
      int within = (hi & 1) * 4;
      bf16x4 lo = *(const bf16x4*)(&stage[rowl * 128 + (c0 ^ sw) * 8 + within]);
      bf16x4 hx = *(const bf16x4*)(&stage[rowl * 128 + ((c0 + 2) ^ sw) * 8 + within]);
      bf16x8 a;
      a[0] = lo[0]; a[1] = lo[1]; a[2] = lo[2]; a[3] = lo[3];
      a[4] = hx[0]; a[5] = hx[1]; a[6] = hx[2]; a[7] = hx[3];
      xf[kt] = a;
    }

    // gemm1: 16 MFMAs -> acc[nt][r] = h1[row][ (w*4+nt)*16 + hi*4 + r ]
    f32x4 acc[4];
    #pragma unroll
    for (int nt = 0; nt < 4; ++nt) acc[nt] = f32x4{0.f, 0.f, 0.f, 0.f};
    #pragma unroll
    for (int nt = 0; nt < 4; ++nt)
      #pragma unroll
      for (int kt = 0; kt < 4; ++kt)
        acc[nt] = __builtin_amdgcn_mfma_f32_16x16x32_bf16(wreg1[kt * 4 + nt], xf[kt],
                                                          acc[nt], 0, 0, 0);

    // bias + relu + pack: gemm1 output frags ARE gemm2 A-frags for k-tiles 2w,2w+1
    bf16x8 xf2[2];
    #pragma unroll
    for (int kt2 = 0; kt2 < 2; ++kt2) {
      bf16x8 t;
      #pragma unroll
      for (int j = 0; j < 8; ++j) {
        int nt = kt2 * 2 + (j >> 2), r = j & 3;
        float v = fmaxf(acc[nt][r] + bb[nt][r], 0.0f);
        __hip_bfloat16 h = __float2bfloat16(v);
        t[j] = *(short*)&h;
      }
      xf2[kt2] = t;
    }

    // gemm2 partial: 16 MFMAs over this wave's k-slice
    f32x4 acc2[8];
    #pragma unroll
    for (int nt2 = 0; nt2 < 8; ++nt2) acc2[nt2] = f32x4{0.f, 0.f, 0.f, 0.f};
    #pragma unroll
    for (int nt2 = 0; nt2 < 8; ++nt2)
      #pragma unroll
      for (int kt2 = 0; kt2 < 2; ++kt2)
        acc2[nt2] = __builtin_amdgcn_mfma_f32_16x16x32_bf16(wreg2[kt2 * 8 + nt2], xf2[kt2],
                                                            acc2[nt2], 0, 0, 0);

    // write partials to LDS (XOR-swizzled: col ^= (row&7)<<2)
    int prow = l & 15;
    #pragma unroll
    for (int nt2 = 0; nt2 < 8; ++nt2) {
      int col = nt2 * 16 + hi * 4;
      int cs = col ^ ((prow & 7) << 2);
      *(f32x4*)(&red[w][prow][cs]) = acc2[nt2];
    }
    __syncthreads();

    // reduce across 4 waves; store bf16 h2 rows
    #pragma unroll
    for (int gi = 0; gi < 2; ++gi) {
      int g = tid * 2 + gi;
      int row = g >> 5, c4 = (g & 31) * 4;
      int cs = c4 ^ ((row & 7) << 2);
      f32x4 s0 = *(const f32x4*)(&red[0][row][cs]);
      f32x4 s1 = *(const f32x4*)(&red[1][row][cs]);
      f32x4 s2 = *(const f32x4*)(&red[2][row][cs]);
      f32x4 s3 = *(const f32x4*)(&red[3][row][cs]);
      f32x4 sm = s0 + s1 + s2 + s3;
      int grow = r0 + s * 16 + row;
      if (grow < n) {
        ushort o[4];
        __hip_bfloat16 h;
        h = __float2bfloat16(sm[0]); o[0] = *(ushort*)&h;
        h = __float2bfloat16(sm[1]); o[1] = *(ushort*)&h;
        h = __float2bfloat16(sm[2]); o[2] = *(ushort*)&h;
        h = __float2bfloat16(sm[3]); o[3] = *(ushort*)&h;
        uint2 pk;
        pk.x = (uint)o[0] | ((uint)o[1] << 16);
        pk.y = (uint)o[2] | ((uint)o[3] << 16);
        *(uint2*)(H2 + (size_t)grow * 128 + c4) = pk;
      }
    }
    __syncthreads();
  }
}

// ---------------- final: aggregate h3 + bias + log_softmax scatter ----------------

__global__ void k_agg3(const float* __restrict__ h3, const int* __restrict__ rp,
                       const int2* __restrict__ cw, const float* __restrict__ b3,
                       const int* __restrict__ l2g, float* __restrict__ out, int n) {
  int i = blockIdx.x * blockDim.x + threadIdx.x;
  if (i >= n) return;
  float a0 = 0.f, a1 = 0.f;
  int e0 = rp[i], e1 = rp[i + 1];
  for (int e = e0; e < e1; ++e) {
    int2 c = cw[e];
    float w = __int_as_float(c.y);
    a0 = fmaf(w, h3[(size_t)c.x * 2 + 0], a0);
    a1 = fmaf(w, h3[(size_t)c.x * 2 + 1], a1);
  }
  a0 += b3[0];
  a1 += b3[1];
  float m = fmaxf(a0, a1);
  float lse = m + logf(expf(a0 - m) + expf(a1 - m));
  int g = l2g[i];
  out[(size_t)g * 2 + 0] = a0 - lse;
  out[(size_t)g * 2 + 1] = a1 - lse;
}

// ---------------- launch ----------------

extern "C" void kernel_launch(void* const* d_in, const int* in_sizes, int n_in,
                              void* d_out, int out_size, void* d_ws, size_t ws_size,
                              hipStream_t stream) {
  const float* building_x = (const float*)d_in[0];
  const int*   l2g        = (const int*)d_in[1];
  const int*   esrc       = (const int*)d_in[2];
  const int*   edst       = (const int*)d_in[3];
  const float* W1 = (const float*)d_in[4];
  const float* b1 = (const float*)d_in[5];
  const float* W2 = (const float*)d_in[6];
  const float* b2 = (const float*)d_in[7];
  const float* W3 = (const float*)d_in[8];
  const float* b3 = (const float*)d_in[9];
  float* out = (float*)d_out;

  const int n_total = in_sizes[0] / F_IN;
  const int n_sub   = in_sizes[1];
  const int E       = in_sizes[2];
  const int Etot    = E + n_sub;          // edges + self-loops
  const int nb      = (n_sub + 255) / 256;

  // ---- workspace ----
  char* base = (char*)d_ws;
  auto al = [](size_t x) { return (x + 255) & ~(size_t)255; };
  size_t t128 = al((size_t)n_sub * 128 * 2);
  ushort* xsub = (ushort*)base;                    // layer-1 gather table
  ushort* xt   = (ushort*)(base + t128);           // agg1 out (gemm12 input)
  ushort* h2b  = (ushort*)(base + 2 * t128);       // gemm12 out (layer-2 gather table)
  size_t off = 3 * t128;
  auto alloc = [&](size_t bytes) -> void* {
    void* p = base + off;
    off += al(bytes);
    return p;
  };
  float* h3   = (float*)alloc((size_t)n_sub * 2 * 4);
  int*   cnt  = (int*)alloc((size_t)n_sub * 4);
  int*   fill = (int*)alloc((size_t)n_sub * 4);
  int*   rp   = (int*)alloc((size_t)(n_sub + 1) * 4);
  float* dis  = (float*)alloc((size_t)n_sub * 4);
  int2*  cw   = (int2*)alloc((size_t)Etot * 8);
  int*   bsum = (int*)alloc((size_t)nb * 4);
  ushort* w1f = (ushort*)alloc((size_t)128 * 256 * 2);
  ushort* w2f = (ushort*)alloc((size_t)256 * 128 * 2);
  (void)ws_size; (void)n_in; (void)out_size;

  const int B = 256;

  // zero edge counts (DMA), repack weights, fused convert+count
  hipMemsetAsync(cnt, 0, (size_t)n_sub * 4, stream);
  k_prep_w<4, 16><<<16, 256, 0, stream>>>(W1, w1f);
  k_prep_w<8, 8><<<16, 256, 0, stream>>>(W2, w2f);
  int prepGrid = ((n_sub * 32 > E ? n_sub * 32 : E) + B - 1) / B;
  k_prep<<<prepGrid, B, 0, stream>>>(building_x, l2g, edst, xsub, cnt, n_sub * 32, E);

  // CSR scans + fill (also pre-fills output with log(1/2))
  k_scan1<<<nb, 256, 0, stream>>>(cnt, rp, bsum, dis, fill, n_sub);
  k_scan2<<<1, 1024, 0, stream>>>(bsum, nb);
  k_scan3<<<(n_sub + B - 1) / B, B, 0, stream>>>(rp, bsum, n_sub, Etot);
  int fillGrid = ((E > 2 * n_total ? E : 2 * n_total) + B - 1) / B;
  k_fill_csr<<<fillGrid, B, 0, stream>>>(esrc, edst, rp, fill, dis, cw, out,
                                         E, n_sub, 2 * n_total);

  int aggBlocks  = (n_sub + 3) / 4;       // 4 waves / 256-thread block
  int gemmBlocks = (n_sub + 127) / 128;   // BM=128

  // Layer 1 aggregate (standalone, high-MLP) -> bf16 xt
  k_aggb<false, false><<<aggBlocks, B, 0, stream>>>(xsub, rp, cw, nullptr, nullptr,
                                                    xt, nullptr, n_sub);

  // Layers 1+2 GEMMs fused: h2 = relu(xt@W1+b1)@W2 -> bf16 h2b (no x1 materialization)
  k_gemm12<<<gemmBlocks, 256, 0, stream>>>(xt, w1f, w2f, b1, h2b, n_sub);

  // Layer 2 aggregate + bias + relu + W3 -> h3
  k_aggb<true, true><<<aggBlocks, B, 0, stream>>>(h2b, rp, cw, b2, W3,
                                                  nullptr, h3, n_sub);

  // Layer 3: aggregate h3 + bias + log_softmax scatter
  k_agg3<<<(n_sub + B - 1) / B, B, 0, stream>>>(h3, rp, cw, b3, l2g, out, n_sub);
}

// Round 11
// 253.411 us; speedup vs baseline: 1.3991x; 1.0771x over previous
//
#include <hip/hip_runtime.h>
#include <hip/hip_bf16.h>

#define F_IN 128

typedef short bf16x8 __attribute__((ext_vector_type(8)));
typedef short bf16x4 __attribute__((ext_vector_type(4)));
typedef float f32x4  __attribute__((ext_vector_type(4)));
typedef float f32x2  __attribute__((ext_vector_type(2)));

// ---------------- fused bf16-convert (building_x -> xsub) + edge count ----------------
// cnt must be zeroed (hipMemsetAsync) before this kernel.

__global__ void k_prep(const float* __restrict__ X, const int* __restrict__ l2g,
                       const int* __restrict__ dst, ushort* __restrict__ xsub,
                       int* __restrict__ cnt, int n32, int E) {
  int i = blockIdx.x * blockDim.x + threadIdx.x;
  if (i < E) atomicAdd(&cnt[dst[i]], 1);
  if (i < n32) {
    int row = i >> 5, c4 = (i & 31) * 4;
    int g = l2g[row];
    float4 v = *(const float4*)(X + (size_t)g * 128 + c4);
    ushort o[4];
    __hip_bfloat16 h;
    h = __float2bfloat16(v.x); o[0] = *(ushort*)&h;
    h = __float2bfloat16(v.y); o[1] = *(ushort*)&h;
    h = __float2bfloat16(v.z); o[2] = *(ushort*)&h;
    h = __float2bfloat16(v.w); o[3] = *(ushort*)&h;
    uint2 pk;
    pk.x = (uint)o[0] | ((uint)o[1] << 16);
    pk.y = (uint)o[2] | ((uint)o[3] << 16);
    *(uint2*)(xsub + (size_t)row * 128 + c4) = pk;
  }
}

// ---------------- CSR scans (row size = cnt + 1, self-loop at slot 0) ----------------

__global__ void k_scan1(const int* __restrict__ cnt, int* __restrict__ rp,
                        int* __restrict__ bsum, float* __restrict__ dis,
                        int* __restrict__ fill, int n) {
  int tid = threadIdx.x;
  int i = blockIdx.x * 256 + tid;
  int v = (i < n) ? cnt[i] + 1 : 0;       // + self-loop
  int orig = v;
  int lane = tid & 63;
  #pragma unroll
  for (int d = 1; d < 64; d <<= 1) {
    int t = __shfl_up(v, d);
    if (lane >= d) v += t;
  }
  __shared__ int wsum[4];
  int wid = tid >> 6;
  if (lane == 63) wsum[wid] = v;
  __syncthreads();
  int off = 0;
  for (int w = 0; w < wid; ++w) off += wsum[w];
  int incl = v + off;
  if (i < n) {
    rp[i]   = incl - orig;
    dis[i]  = rsqrtf((float)orig);
    fill[i] = 1;                          // slot 0 reserved for self
  }
  if (tid == 255) bsum[blockIdx.x] = incl;
}

__global__ void k_scan2(int* __restrict__ bsum, int nb) {
  __shared__ int s[1024];
  int tid = threadIdx.x;
  int v = (tid < nb) ? bsum[tid] : 0;
  s[tid] = v;
  __syncthreads();
  for (int d = 1; d < 1024; d <<= 1) {
    int t = (tid >= d) ? s[tid - d] : 0;
    __syncthreads();
    s[tid] += t;
    __syncthreads();
  }
  if (tid < nb) bsum[tid] = s[tid] - v;
}

__global__ void k_scan3(int* __restrict__ rp, const int* __restrict__ bsum, int n, int Etot) {
  int i = blockIdx.x * blockDim.x + threadIdx.x;
  if (i < n) rp[i] += bsum[i >> 8];
  if (i == 0) rp[n] = Etot;
}

// edges at slots >=1; self (i, dis_i^2) at slot 0; also pre-fills the output tensor
__global__ void k_fill_csr(const int* __restrict__ src, const int* __restrict__ dst,
                           const int* __restrict__ rp, int* __restrict__ fill,
                           const float* __restrict__ dis,
                           int2* __restrict__ cw, float* __restrict__ out,
                           int E, int n, int outtot) {
  int e = blockIdx.x * blockDim.x + threadIdx.x;
  if (e < outtot) out[e] = -0.69314718055994531f;   // log(1/2)
  if (e < n) {
    float d = dis[e];
    cw[rp[e]] = make_int2(e, __float_as_int(d * d));
  }
  if (e < E) {
    int s = src[e], d = dst[e];
    int pos = rp[d] + atomicAdd(&fill[d], 1);
    cw[pos] = make_int2(s, __float_as_int(dis[s] * dis[d]));
  }
}

// ---------------- aggregation: 4 groups x 16 lanes x 16B, pipelined gathers -----------
// One wave per node. The node's edge records cw[e0..e0+deg) are CONTIGUOUS: one
// coalesced 8B/lane load grabs the whole row; per-iteration (s,w) come from two
// __shfl broadcasts (no memory dep). Manual 2-round unroll puts 8 row-gathers in
// flight before the first FMA. Exec-masked guards: no wasted gather traffic.
// FUSEW3 folds the 128x2 GEMM into the epilogue (writes h3[2] instead of the row).

template <bool BIASRELU, bool FUSEW3>
__global__ void k_aggb(const ushort* __restrict__ X, const int* __restrict__ rp,
                       const int2* __restrict__ cw, const float* __restrict__ bias,
                       const float* __restrict__ W3,
                       ushort* __restrict__ outp, float* __restrict__ h3, int n) {
  int wavei = (int)((blockIdx.x * (size_t)blockDim.x + threadIdx.x) >> 6);
  int lane = threadIdx.x & 63;
  if (wavei >= n) return;
  int q = lane >> 4, ln = lane & 15;
  int e0 = rp[wavei], deg = rp[wavei + 1] - e0;   // >= 1 (self at slot 0)

  // whole edge row in registers: lane i holds slot i (coalesced single load)
  int2 cme = make_int2(0, 0);
  if (lane < deg) cme = cw[e0 + lane];

  f32x2 acc[4];
  #pragma unroll
  for (int j = 0; j < 4; ++j) acc[j] = f32x2{0.f, 0.f};

  int dmax = deg < 64 ? deg : 64;
  for (int t0 = 0; t0 < dmax; t0 += 8) {
    int iA = t0 + q, iB = t0 + 4 + q;
    bool mA = iA < dmax, mB = iB < dmax;
    int   sA = __shfl(cme.x, iA);
    float wA = __int_as_float(__shfl(cme.y, iA));
    int   sB = __shfl(cme.x, iB);
    float wB = __int_as_float(__shfl(cme.y, iB));
    uint4 rA = make_uint4(0u, 0u, 0u, 0u);
    uint4 rB = make_uint4(0u, 0u, 0u, 0u);
    if (mA) rA = *(const uint4*)((const char*)X + (((uint)sA << 8) + ((uint)ln << 4)));
    if (mB) rB = *(const uint4*)((const char*)X + (((uint)sB << 8) + ((uint)ln << 4)));
    if (mA) {
      uint u[4] = {rA.x, rA.y, rA.z, rA.w};
      f32x2 wv = {wA, wA};
      #pragma unroll
      for (int tt = 0; tt < 4; ++tt) {
        f32x2 v;
        v.x = __uint_as_float(u[tt] << 16);
        v.y = __uint_as_float(u[tt] & 0xffff0000u);
        acc[tt] += wv * v;
      }
    }
    if (mB) {
      uint u[4] = {rB.x, rB.y, rB.z, rB.w};
      f32x2 wv = {wB, wB};
      #pragma unroll
      for (int tt = 0; tt < 4; ++tt) {
        f32x2 v;
        v.x = __uint_as_float(u[tt] << 16);
        v.y = __uint_as_float(u[tt] & 0xffff0000u);
        acc[tt] += wv * v;
      }
    }
  }

  // rare tail: deg > 64 (direct cw reads, old path)
  for (int t0 = 64; t0 < deg; t0 += 4) {
    int t = t0 + q;
    if (t < deg) {
      int2 c = cw[e0 + t];
      float w = __int_as_float(c.y);
      uint4 r = *(const uint4*)((const char*)X + (((uint)c.x << 8) + ((uint)ln << 4)));
      uint u[4] = {r.x, r.y, r.z, r.w};
      f32x2 wv = {w, w};
      #pragma unroll
      for (int tt = 0; tt < 4; ++tt) {
        f32x2 v;
        v.x = __uint_as_float(u[tt] << 16);
        v.y = __uint_as_float(u[tt] & 0xffff0000u);
        acc[tt] += wv * v;
      }
    }
  }

  // reduce across the 4 groups (lane bits 4,5)
  #pragma unroll
  for (int j = 0; j < 4; ++j) {
    acc[j].x += __shfl_xor(acc[j].x, 16);
    acc[j].y += __shfl_xor(acc[j].y, 16);
    acc[j].x += __shfl_xor(acc[j].x, 32);
    acc[j].y += __shfl_xor(acc[j].y, 32);
  }

  if (lane < 16) {
    if (BIASRELU) {
      float4 b0 = *(const float4*)(bias + ln * 8);
      float4 b1 = *(const float4*)(bias + ln * 8 + 4);
      acc[0].x = fmaxf(acc[0].x + b0.x, 0.f);
      acc[0].y = fmaxf(acc[0].y + b0.y, 0.f);
      acc[1].x = fmaxf(acc[1].x + b0.z, 0.f);
      acc[1].y = fmaxf(acc[1].y + b0.w, 0.f);
      acc[2].x = fmaxf(acc[2].x + b1.x, 0.f);
      acc[2].y = fmaxf(acc[2].y + b1.y, 0.f);
      acc[3].x = fmaxf(acc[3].x + b1.z, 0.f);
      acc[3].y = fmaxf(acc[3].y + b1.w, 0.f);
    }
    if (FUSEW3) {
      const float4* w3p = (const float4*)(W3 + ln * 16);
      float p0 = 0.f, p1 = 0.f;
      #pragma unroll
      for (int j2 = 0; j2 < 4; ++j2) {
        float4 wa = w3p[j2];
        p0 = fmaf(acc[j2].x, wa.x, p0);
        p1 = fmaf(acc[j2].x, wa.y, p1);
        p0 = fmaf(acc[j2].y, wa.z, p0);
        p1 = fmaf(acc[j2].y, wa.w, p1);
      }
      p0 += __shfl_xor(p0, 1); p1 += __shfl_xor(p1, 1);
      p0 += __shfl_xor(p0, 2); p1 += __shfl_xor(p1, 2);
      p0 += __shfl_xor(p0, 4); p1 += __shfl_xor(p1, 4);
      p0 += __shfl_xor(p0, 8); p1 += __shfl_xor(p1, 8);
      if (ln == 0) {
        float2 rr = make_float2(p0, p1);
        *(float2*)(h3 + (size_t)wavei * 2) = rr;
      }
    } else {
      uint pk[4];
      #pragma unroll
      for (int j2 = 0; j2 < 4; ++j2) {
        __hip_bfloat16 hx = __float2bfloat16(acc[j2].x);
        __hip_bfloat16 hy = __float2bfloat16(acc[j2].y);
        pk[j2] = (uint)(*(ushort*)&hx) | ((uint)(*(ushort*)&hy) << 16);
      }
      uint4 sv = make_uint4(pk[0], pk[1], pk[2], pk[3]);
      *(uint4*)((char*)outp + (((size_t)wavei << 8) + ((uint)ln << 4))) = sv;
    }
  }
}

// ---------------- W -> fragment-major bf16 repack ----------------
// lane l holds W[k = kt*32 + (l>>4)*4 + (j&3) + 16*(j>>2)][col = nt*16 + (l&15)]

template <int KT, int NT>
__global__ void k_prep_w(const float* __restrict__ W, ushort* __restrict__ WF) {
  int tid = blockIdx.x * 256 + threadIdx.x;
  if (tid >= KT * NT * 64) return;
  int l  = tid & 63;
  int nt = (tid >> 6) % NT;
  int kt = tid / (64 * NT);
  int colc = nt * 16 + (l & 15);
  int kbase = kt * 32 + (l >> 4) * 4;
  ushort v[8];
  #pragma unroll
  for (int j = 0; j < 8; ++j) {
    int k = kbase + (j & 3) + 16 * (j >> 2);
    __hip_bfloat16 h = __float2bfloat16(W[(size_t)k * (NT * 16) + colc]);
    v[j] = *(ushort*)&h;
  }
  uint4 pk;
  pk.x = (uint)v[0] | ((uint)v[1] << 16);
  pk.y = (uint)v[2] | ((uint)v[3] << 16);
  pk.z = (uint)v[4] | ((uint)v[5] << 16);
  pk.w = (uint)v[6] | ((uint)v[7] << 16);
  *(uint4*)(WF + (size_t)tid * 8) = pk;
}

// ---------------- FUSED GEMM1+GEMM2: xt[n,128] -> h2 = relu(xt@W1+b1)@W2 -> bf16 ------
// Block = 256 threads (4 waves), BM = 128 rows.
// gemm1: wave w owns output cols [w*64, w*64+64) (W1 frags in registers).
// Handoff: those cols ARE gemm2's k-slice (k-tiles 2w, 2w+1); the gemm1 output
// fragment layout equals the gemm2 A-fragment layout:
//   xf2[kt2][j] = bf16(relu(acc[kt2*2+(j>>2)][j&3] + b1)).
// gemm2: each wave computes a 16x128 partial (its k-slice) per row-subtile;
// partials summed across the 4 waves via XOR-swizzled LDS, stored bf16.

__global__ __launch_bounds__(256) void k_gemm12(const ushort* __restrict__ A,
                                                const ushort* __restrict__ WF1,
                                                const ushort* __restrict__ WF2,
                                                const float* __restrict__ bias1,
                                                ushort* __restrict__ H2, int n) {
  __shared__ short stage[128 * 128];       // 32 KB bf16 input tile
  __shared__ float red[4][16][128];        // 32 KB f32 partial-sum buffer

  int tid = threadIdx.x;
  int r0 = blockIdx.x * 128;
  int l  = tid & 63;
  int w  = tid >> 6;
  int hi = l >> 4;

  // W1 fragments for this wave's N-slice (cols w*64..w*64+63): nt = w*4..w*4+3
  bf16x8 wreg1[16];
  #pragma unroll
  for (int kt = 0; kt < 4; ++kt)
    #pragma unroll
    for (int nt = 0; nt < 4; ++nt)
      wreg1[kt * 4 + nt] =
          *(const bf16x8*)(WF1 + ((size_t)(kt * 16 + w * 4 + nt) * 64 + l) * 8);

  // W2 fragments for this wave's k-slice (k-tiles 2w, 2w+1), all 8 n-tiles
  bf16x8 wreg2[16];
  #pragma unroll
  for (int kt2 = 0; kt2 < 2; ++kt2)
    #pragma unroll
    for (int nt2 = 0; nt2 < 8; ++nt2)
      wreg2[kt2 * 8 + nt2] =
          *(const bf16x8*)(WF2 + ((size_t)((w * 2 + kt2) * 8 + nt2) * 64 + l) * 8);

  // bias1 for this wave's col slice
  float bb[4][4];
  #pragma unroll
  for (int nt = 0; nt < 4; ++nt) {
    float4 b4 = *(const float4*)(bias1 + (w * 4 + nt) * 16 + hi * 4);
    bb[nt][0] = b4.x; bb[nt][1] = b4.y; bb[nt][2] = b4.z; bb[nt][3] = b4.w;
  }

  // stage xt tile (coalesced 16B loads, XOR-swizzled 16B chunks; 16 chunks/row)
  #pragma unroll
  for (int p = 0; p < 8; ++p) {
    int idx = p * 256 + tid;
    int row = idx >> 4, c = idx & 15;
    uint4 v = make_uint4(0u, 0u, 0u, 0u);
    if (r0 + row < n) v = *(const uint4*)(A + (size_t)(r0 + row) * 128 + c * 8);
    *(uint4*)(&stage[row * 128 + ((c ^ (row & 15)) * 8)]) = v;
  }
  __syncthreads();

  int sw = l & 15;
  for (int s = 0; s < 8; ++s) {
    int rowl = s * 16 + (l & 15);
    // gemm1 X-fragments from LDS
    bf16x8 xf[4];
    #pragma unroll
    for (int kt = 0; kt < 4; ++kt) {
      int c0 = kt * 4 + (hi >> 1);
      int within = (hi & 1) * 4;
      bf16x4 lo = *(const bf16x4*)(&stage[rowl * 128 + (c0 ^ sw) * 8 + within]);
      bf16x4 hx = *(const bf16x4*)(&stage[rowl * 128 + ((c0 + 2) ^ sw) * 8 + within]);
      bf16x8 a;
      a[0] = lo[0]; a[1] = lo[1]; a[2] = lo[2]; a[3] = lo[3];
      a[4] = hx[0]; a[5] = hx[1]; a[6] = hx[2]; a[7] = hx[3];
      xf[kt] = a;
    }

    // gemm1: 16 MFMAs -> acc[nt][r] = h1[row][ (w*4+nt)*16 + hi*4 + r ]
    f32x4 acc[4];
    #pragma unroll
    for (int nt = 0; nt < 4; ++nt) acc[nt] = f32x4{0.f, 0.f, 0.f, 0.f};
    #pragma unroll
    for (int nt = 0; nt < 4; ++nt)
      #pragma unroll
      for (int kt = 0; kt < 4; ++kt)
        acc[nt] = __builtin_amdgcn_mfma_f32_16x16x32_bf16(wreg1[kt * 4 + nt], xf[kt],
                                                          acc[nt], 0, 0, 0);

    // bias + relu + pack: gemm1 output frags ARE gemm2 A-frags for k-tiles 2w,2w+1
    bf16x8 xf2[2];
    #pragma unroll
    for (int kt2 = 0; kt2 < 2; ++kt2) {
      bf16x8 t;
      #pragma unroll
      for (int j = 0; j < 8; ++j) {
        int nt = kt2 * 2 + (j >> 2), r = j & 3;
        float v = fmaxf(acc[nt][r] + bb[nt][r], 0.0f);
        __hip_bfloat16 h = __float2bfloat16(v);
        t[j] = *(short*)&h;
      }
      xf2[kt2] = t;
    }

    // gemm2 partial: 16 MFMAs over this wave's k-slice
    f32x4 acc2[8];
    #pragma unroll
    for (int nt2 = 0; nt2 < 8; ++nt2) acc2[nt2] = f32x4{0.f, 0.f, 0.f, 0.f};
    #pragma unroll
    for (int nt2 = 0; nt2 < 8; ++nt2)
      #pragma unroll
      for (int kt2 = 0; kt2 < 2; ++kt2)
        acc2[nt2] = __builtin_amdgcn_mfma_f32_16x16x32_bf16(wreg2[kt2 * 8 + nt2], xf2[kt2],
                                                            acc2[nt2], 0, 0, 0);

    // write partials to LDS (XOR-swizzled: col ^= (row&7)<<2)
    int prow = l & 15;
    #pragma unroll
    for (int nt2 = 0; nt2 < 8; ++nt2) {
      int col = nt2 * 16 + hi * 4;
      int cs = col ^ ((prow & 7) << 2);
      *(f32x4*)(&red[w][prow][cs]) = acc2[nt2];
    }
    __syncthreads();

    // reduce across 4 waves; store bf16 h2 rows
    #pragma unroll
    for (int gi = 0; gi < 2; ++gi) {
      int g = tid * 2 + gi;
      int row = g >> 5, c4 = (g & 31) * 4;
      int cs = c4 ^ ((row & 7) << 2);
      f32x4 s0 = *(const f32x4*)(&red[0][row][cs]);
      f32x4 s1 = *(const f32x4*)(&red[1][row][cs]);
      f32x4 s2 = *(const f32x4*)(&red[2][row][cs]);
      f32x4 s3 = *(const f32x4*)(&red[3][row][cs]);
      f32x4 sm = s0 + s1 + s2 + s3;
      int grow = r0 + s * 16 + row;
      if (grow < n) {
        ushort o[4];
        __hip_bfloat16 h;
        h = __float2bfloat16(sm[0]); o[0] = *(ushort*)&h;
        h = __float2bfloat16(sm[1]); o[1] = *(ushort*)&h;
        h = __float2bfloat16(sm[2]); o[2] = *(ushort*)&h;
        h = __float2bfloat16(sm[3]); o[3] = *(ushort*)&h;
        uint2 pk;
        pk.x = (uint)o[0] | ((uint)o[1] << 16);
        pk.y = (uint)o[2] | ((uint)o[3] << 16);
        *(uint2*)(H2 + (size_t)grow * 128 + c4) = pk;
      }
    }
    __syncthreads();
  }
}

// ---------------- final: aggregate h3 + bias + log_softmax scatter ----------------

__global__ void k_agg3(const float* __restrict__ h3, const int* __restrict__ rp,
                       const int2* __restrict__ cw, const float* __restrict__ b3,
                       const int* __restrict__ l2g, float* __restrict__ out, int n) {
  int i = blockIdx.x * blockDim.x + threadIdx.x;
  if (i >= n) return;
  float a0 = 0.f, a1 = 0.f;
  int e0 = rp[i], e1 = rp[i + 1];
  for (int e = e0; e < e1; ++e) {
    int2 c = cw[e];
    float w = __int_as_float(c.y);
    a0 = fmaf(w, h3[(size_t)c.x * 2 + 0], a0);
    a1 = fmaf(w, h3[(size_t)c.x * 2 + 1], a1);
  }
  a0 += b3[0];
  a1 += b3[1];
  float m = fmaxf(a0, a1);
  float lse = m + logf(expf(a0 - m) + expf(a1 - m));
  int g = l2g[i];
  out[(size_t)g * 2 + 0] = a0 - lse;
  out[(size_t)g * 2 + 1] = a1 - lse;
}

// ---------------- launch ----------------

extern "C" void kernel_launch(void* const* d_in, const int* in_sizes, int n_in,
                              void* d_out, int out_size, void* d_ws, size_t ws_size,
                              hipStream_t stream) {
  const float* building_x = (const float*)d_in[0];
  const int*   l2g        = (const int*)d_in[1];
  const int*   esrc       = (const int*)d_in[2];
  const int*   edst       = (const int*)d_in[3];
  const float* W1 = (const float*)d_in[4];
  const float* b1 = (const float*)d_in[5];
  const float* W2 = (const float*)d_in[6];
  const float* b2 = (const float*)d_in[7];
  const float* W3 = (const float*)d_in[8];
  const float* b3 = (const float*)d_in[9];
  float* out = (float*)d_out;

  const int n_total = in_sizes[0] / F_IN;
  const int n_sub   = in_sizes[1];
  const int E       = in_sizes[2];
  const int Etot    = E + n_sub;          // edges + self-loops
  const int nb      = (n_sub + 255) / 256;

  // ---- workspace ----
  char* base = (char*)d_ws;
  auto al = [](size_t x) { return (x + 255) & ~(size_t)255; };
  size_t t128 = al((size_t)n_sub * 128 * 2);
  ushort* xsub = (ushort*)base;                    // layer-1 gather table
  ushort* xt   = (ushort*)(base + t128);           // agg1 out (gemm12 input)
  ushort* h2b  = (ushort*)(base + 2 * t128);       // gemm12 out (layer-2 gather table)
  size_t off = 3 * t128;
  auto alloc = [&](size_t bytes) -> void* {
    void* p = base + off;
    off += al(bytes);
    return p;
  };
  float* h3   = (float*)alloc((size_t)n_sub * 2 * 4);
  int*   cnt  = (int*)alloc((size_t)n_sub * 4);
  int*   fill = (int*)alloc((size_t)n_sub * 4);
  int*   rp   = (int*)alloc((size_t)(n_sub + 1) * 4);
  float* dis  = (float*)alloc((size_t)n_sub * 4);
  int2*  cw   = (int2*)alloc((size_t)Etot * 8);
  int*   bsum = (int*)alloc((size_t)nb * 4);
  ushort* w1f = (ushort*)alloc((size_t)128 * 256 * 2);
  ushort* w2f = (ushort*)alloc((size_t)256 * 128 * 2);
  (void)ws_size; (void)n_in; (void)out_size;

  const int B = 256;

  // zero edge counts (DMA), repack weights, fused convert+count
  hipMemsetAsync(cnt, 0, (size_t)n_sub * 4, stream);
  k_prep_w<4, 16><<<16, 256, 0, stream>>>(W1, w1f);
  k_prep_w<8, 8><<<16, 256, 0, stream>>>(W2, w2f);
  int prepGrid = ((n_sub * 32 > E ? n_sub * 32 : E) + B - 1) / B;
  k_prep<<<prepGrid, B, 0, stream>>>(building_x, l2g, edst, xsub, cnt, n_sub * 32, E);

  // CSR scans + fill (also pre-fills output with log(1/2))
  k_scan1<<<nb, 256, 0, stream>>>(cnt, rp, bsum, dis, fill, n_sub);
  k_scan2<<<1, 1024, 0, stream>>>(bsum, nb);
  k_scan3<<<(n_sub + B - 1) / B, B, 0, stream>>>(rp, bsum, n_sub, Etot);
  int fillGrid = ((E > 2 * n_total ? E : 2 * n_total) + B - 1) / B;
  k_fill_csr<<<fillGrid, B, 0, stream>>>(esrc, edst, rp, fill, dis, cw, out,
                                         E, n_sub, 2 * n_total);

  int aggBlocks  = (n_sub + 3) / 4;       // 4 waves / 256-thread block
  int gemmBlocks = (n_sub + 127) / 128;   // BM=128

  // Layer 1 aggregate (standalone, pipelined gathers) -> bf16 xt
  k_aggb<false, false><<<aggBlocks, B, 0, stream>>>(xsub, rp, cw, nullptr, nullptr,
                                                    xt, nullptr, n_sub);

  // Layers 1+2 GEMMs fused: h2 = relu(xt@W1+b1)@W2 -> bf16 h2b (no x1 materialization)
  k_gemm12<<<gemmBlocks, 256, 0, stream>>>(xt, w1f, w2f, b1, h2b, n_sub);

  // Layer 2 aggregate + bias + relu + W3 -> h3
  k_aggb<true, true><<<aggBlocks, B, 0, stream>>>(h2b, rp, cw, b2, W3,
                                                  nullptr, h3, n_sub);

  // Layer 3: aggregate h3 + bias + log_softmax scatter
  k_agg3<<<(n_sub + B - 1) / B, B, 0, stream>>>(h3, rp, cw, b3, l2g, out, n_sub);
}